// Round 1
// baseline (459.924 us; speedup 1.0000x reference)
//
#include <hip/hip_runtime.h>

#define B_ 256
#define T_ 2048
#define F_ 20
#define NT (B_*T_)

__device__ __forceinline__ float ex2(float x){ return __builtin_amdgcn_exp2f(x); }
__device__ __forceinline__ float rcpf_(float x){ return __builtin_amdgcn_rcpf(x); }

// constants
// 20*log2(e), 2*log2(e), log2(e)
#define K10F 28.853900817779268f
#define K1F   2.8853900817779268f
#define LOG2E 1.4426950408889634f

__device__ __forceinline__ float hside(float x){ // (tanh(10x)+1)/2
  return 1.0f - rcpf_(ex2(K10F*x) + 1.0f);
}
__device__ __forceinline__ float tanh_f(float z){
  return 1.0f - 2.0f*rcpf_(ex2(K1F*z) + 1.0f);
}
__device__ __forceinline__ float sigmoid_f(float z){
  return rcpf_(1.0f + ex2(-LOG2E*z));
}

// ws layout (floats):
// petT  [0,   NT)      t-major: idx = t*B + b
// pT    [NT,  2NT)
// wuT   [2NT, 3NT)
// wlT   [3NT, 4NT)
// wdT   [4NT, 5NT)
// params[5NT, 13NT)    8 per row, row index r = t*B + b

__global__ __launch_bounds__(256) void prep_kernel(const float* __restrict__ in,
                                                   float* __restrict__ ws){
  int r = blockIdx.x*256 + threadIdx.x;
  if (r >= NT) return;
  int b = r & (B_-1);
  int t = r >> 8;
  const float* src = in + ((size_t)b*T_ + t)*F_;
  ws[r]      = src[0]; // pet
  ws[NT + r] = src[2]; // p
}

__global__ __launch_bounds__(256) void fused_kernel(const float* __restrict__ in,
    const float* __restrict__ w1, const float* __restrict__ b1,
    const float* __restrict__ w2, const float* __restrict__ b2,
    const float* __restrict__ w3, const float* __restrict__ b3,
    float* __restrict__ ws){
  const float* petT = ws;
  const float* pT   = ws + NT;
  float* wuT = ws + 2*(size_t)NT;
  float* wlT = ws + 3*(size_t)NT;
  float* wdT = ws + 4*(size_t)NT;
  float* params = ws + 5*(size_t)NT;

  if (blockIdx.x == 0) {
    // ---- sequential Xinanjiang scan: one lane per batch element ----
    int b = threadIdx.x; // 0..255
    float wu = 0.0f, wl = 0.0f, wd = 0.0f;
    const int CH = 8;
    float pA[CH], qA[CH], pB[CH], qB[CH];

    auto loadChunk = [&](int c, float* pp, float* qq){
      #pragma unroll
      for (int i = 0; i < CH; ++i){
        int idx = (c*CH + i)*B_ + b;
        pp[i] = petT[idx];
        qq[i] = pT[idx];
      }
    };
    auto doSteps = [&](int c, const float* pp, const float* qq){
      #pragma unroll
      for (int i = 0; i < CH; ++i){
        float pet = pp[i], p = qq[i];
        float d   = wu - pet;
        float r1  = rcpf_(ex2(K10F*d) + 1.0f);
        float d1  = -d*r1;                             // = pet - et1
        float rp  = fmaf(-d1, rcpf_(ex2(K10F*d1) + 1.0f), d1);  // h(d1)*d1
        float d2  = rp - wl;
        float et22= fmaf(d2, rcpf_(ex2(K10F*d2) + 1.0f), wl);   // wl + d2*r2
        float et2 = (1.0f - rcpf_(ex2(K10F*rp) + 1.0f)) * et22; // h(rp)*et22
        float q   = rp - et2;
        float d3  = q - wd;
        float et33= fmaf(d3, rcpf_(ex2(K10F*d3) + 1.0f), wd);   // wd + d3*r3
        float et3 = (1.0f - rcpf_(ex2(K10F*q) + 1.0f)) * et33;  // h(q)*et33
        float base = (p - pet) + d1;                   // p - et1 (clip never binds)
        wu += base;
        wl += base - et2;
        wd += base - et2 - et3;
        int idx = (c*CH + i)*B_ + b;
        wuT[idx] = wu; wlT[idx] = wl; wdT[idx] = wd;
      }
    };

    const int NC = T_/CH; // 256 chunks, even
    loadChunk(0, pA, qA);
    for (int c = 0; c < NC; c += 2){
      loadChunk(c+1, pB, qB);
      doSteps(c, pA, qA);
      if (c + 2 < NC) loadChunk(c+2, pA, qA);
      doSteps(c+1, pB, qB);
    }
  } else {
    // ---- MLP: one row per thread, weights via wave-uniform (scalar) loads ----
    int r = (blockIdx.x - 1)*256 + threadIdx.x; // < NT
    int b = r & (B_-1);
    int t = r >> 8;
    const float* row = in + ((size_t)b*T_ + t)*F_ + 5;
    float a[15];
    #pragma unroll
    for (int i = 0; i < 15; ++i) a[i] = row[i];
    float acc[64];
    #pragma unroll
    for (int k = 0; k < 64; ++k) acc[k] = b2[k];
    for (int j = 0; j < 256; ++j){
      float z = b1[j];
      #pragma unroll
      for (int i = 0; i < 15; ++i) z = fmaf(a[i], w1[i*256 + j], z);
      float h = tanh_f(z);
      #pragma unroll
      for (int k = 0; k < 64; ++k) acc[k] = fmaf(h, w2[j*64 + k], acc[k]);
    }
    #pragma unroll
    for (int k = 0; k < 64; ++k) acc[k] = tanh_f(acc[k]);
    float pr[8];
    #pragma unroll
    for (int m = 0; m < 8; ++m){
      float z = b3[m];
      #pragma unroll
      for (int k = 0; k < 64; ++k) z = fmaf(acc[k], w3[k*8 + m], z);
      pr[m] = sigmoid_f(z);
    }
    float4* dst = (float4*)(params + (size_t)r*8);
    dst[0] = make_float4(pr[0], pr[1], pr[2], pr[3]);
    dst[1] = make_float4(pr[4], pr[5], pr[6], pr[7]);
  }
}

__global__ __launch_bounds__(256) void final_kernel(const float* __restrict__ ws,
                                                    float* __restrict__ out){
  int r = blockIdx.x*256 + threadIdx.x;
  if (r >= NT) return;
  const float* petT = ws;
  const float* pT   = ws + NT;
  const float* wuT  = ws + 2*(size_t)NT;
  const float* wlT  = ws + 3*(size_t)NT;
  const float* wdT  = ws + 4*(size_t)NT;
  const float* params = ws + 5*(size_t)NT;

  float pet = petT[r]; (void)pet; // not used in epilogue (evap result is dead code)
  float p  = pT[r];
  float wu = wuT[r], wl = wlT[r], wd = wdT[r];
  (void)wl;
  const float4* pp = (const float4*)(params + (size_t)r*8);
  float4 p0 = pp[0], p1 = pp[1];
  // p0: wum, wlm, wdm, b  |  p1: c, k1, k2, k3
  // NOTE reference calls _runoff(wu, wd, wl, p, wum, wdm, wlm, b, c):
  //   arg wl <- state wd, arg wlm <- param wdm, arg wdm <- param wlm
  float wum   = fmaf(p0.x, 19.9f, 0.1f);
  float wlm_s = fmaf(p0.z, 30.0f, 60.0f);  // wdm param lands in wlm slot
  float wdm_s = fmaf(p0.y, 60.0f, 60.0f);  // wlm param lands in wdm slot
  float cc = fmaf(p1.x, 0.19f, 0.01f);
  float bb = fmaf(p0.w, 0.30f, 0.10f);
  float wt = wum + wlm_s + wdm_s;
  float xu = wu / wt;
  float xd = wd / wt;                       // "wl" inside _runoff is state wd
  float s  = cc*xu*xu + bb*xd*xd;
  float ps = p - s;
  float runoff = hside(ps)*ps;
  float k1p = fmaf(p1.y, 0.69f, 0.01f);
  float k2p = fmaf(p1.z, 0.69f, 0.01f);
  float k3p = fmaf(p1.w, 0.89f, 0.01f);
  float sr  = k1p*runoff;
  float itf = k2p*(runoff - sr);
  float bf  = k3p*(runoff - sr - itf);
  int b = r & (B_-1);
  int t = r >> 8;
  out[(size_t)b*T_ + t] = sr + 0.5f*itf + 0.25f*bf;
}

extern "C" void kernel_launch(void* const* d_in, const int* in_sizes, int n_in,
                              void* d_out, int out_size, void* d_ws, size_t ws_size,
                              hipStream_t stream) {
  const float* in = (const float*)d_in[0];
  const float* w1 = (const float*)d_in[1];
  const float* b1 = (const float*)d_in[2];
  const float* w2 = (const float*)d_in[3];
  const float* b2 = (const float*)d_in[4];
  const float* w3 = (const float*)d_in[5];
  const float* b3 = (const float*)d_in[6];
  float* out = (float*)d_out;
  float* ws  = (float*)d_ws;

  prep_kernel <<<NT/256,     256, 0, stream>>>(in, ws);
  fused_kernel<<<NT/256 + 1, 256, 0, stream>>>(in, w1, b1, w2, b2, w3, b3, ws);
  final_kernel<<<NT/256,     256, 0, stream>>>(ws, out);
}

// Round 2
// 358.639 us; speedup vs baseline: 1.2824x; 1.2824x over previous
//
#include <hip/hip_runtime.h>

#define B_ 256
#define T_ 2048
#define F_ 20
#define NT (B_*T_)

typedef __bf16 bf16x8 __attribute__((ext_vector_type(8)));
typedef float  f32x4  __attribute__((ext_vector_type(4)));

__device__ __forceinline__ float ex2(float x){ return __builtin_amdgcn_exp2f(x); }
__device__ __forceinline__ float rcpf_(float x){ return __builtin_amdgcn_rcpf(x); }

// 20*log2(e), 2*log2(e), log2(e)
#define K10F 28.853900817779268f
#define K1F   2.8853900817779268f
#define LOG2E 1.4426950408889634f

__device__ __forceinline__ float hside(float x){ return 1.0f - rcpf_(ex2(K10F*x) + 1.0f); }
__device__ __forceinline__ float tanh_f(float z){ return 1.0f - 2.0f*rcpf_(ex2(K1F*z) + 1.0f); }
__device__ __forceinline__ float sigmoid_f(float z){ return rcpf_(1.0f + ex2(-LOG2E*z)); }

// ws layout (floats):
// petT  [0,   NT)      t-major: idx = t*B + b
// pT    [NT,  2NT)
// wuT   [2NT, 3NT)
// wlT   [3NT, 4NT)
// wdT   [4NT, 5NT)
// params[5NT, 13NT)    8 per row, row index r: b = r&255, t = r>>8

__global__ __launch_bounds__(256) void prep_kernel(const float* __restrict__ in,
                                                   float* __restrict__ ws){
  int r = blockIdx.x*256 + threadIdx.x;
  if (r >= NT) return;
  int b = r & (B_-1);
  int t = r >> 8;
  const float* src = in + ((size_t)b*T_ + t)*F_;
  ws[r]      = src[0]; // pet
  ws[NT + r] = src[2]; // p
}

// fused: block 0 = sequential scan (256 lanes); blocks 1..4096 = MFMA MLP (128 rows each)
__global__ __launch_bounds__(512) void fused_kernel(const float* __restrict__ in,
    const float* __restrict__ w1, const float* __restrict__ b1,
    const float* __restrict__ w2, const float* __restrict__ b2,
    const float* __restrict__ w3, const float* __restrict__ b3,
    float* __restrict__ ws){
  const float* petT = ws;
  const float* pT   = ws + NT;
  float* wuT = ws + 2*(size_t)NT;
  float* wlT = ws + 3*(size_t)NT;
  float* wdT = ws + 4*(size_t)NT;
  float* params = ws + 5*(size_t)NT;

  if (blockIdx.x == 0) {
    // ---- sequential Xinanjiang scan: one lane per batch element ----
    if (threadIdx.x >= 256) return;
    int b = threadIdx.x;
    float wu = 0.0f, wl = 0.0f, wd = 0.0f;
    const int CH = 8;
    float pA[CH], qA[CH], pB[CH], qB[CH];

    auto loadChunk = [&](int c, float* pp, float* qq){
      #pragma unroll
      for (int i = 0; i < CH; ++i){
        int idx = (c*CH + i)*B_ + b;
        pp[i] = petT[idx];
        qq[i] = pT[idx];
      }
    };
    auto doSteps = [&](int c, const float* pp, const float* qq){
      #pragma unroll
      for (int i = 0; i < CH; ++i){
        float pet = pp[i], p = qq[i];
        float d   = wu - pet;
        float r1  = rcpf_(ex2(K10F*d) + 1.0f);
        float d1  = -d*r1;                                      // pet - et1
        float rp  = fmaf(-d1, rcpf_(ex2(K10F*d1) + 1.0f), d1);  // h(d1)*d1
        float d2  = rp - wl;
        float et22= fmaf(d2, rcpf_(ex2(K10F*d2) + 1.0f), wl);
        float et2 = (1.0f - rcpf_(ex2(K10F*rp) + 1.0f)) * et22;
        float qv  = rp - et2;
        float d3  = qv - wd;
        float et33= fmaf(d3, rcpf_(ex2(K10F*d3) + 1.0f), wd);
        float et3 = (1.0f - rcpf_(ex2(K10F*qv) + 1.0f)) * et33;
        float base = (p - pet) + d1;                            // p - et1
        wu += base;
        wl += base - et2;
        wd += base - et2 - et3;
        int idx = (c*CH + i)*B_ + b;
        wuT[idx] = wu; wlT[idx] = wl; wdT[idx] = wd;
      }
    };

    const int NC = T_/CH;
    loadChunk(0, pA, qA);
    for (int c = 0; c < NC; c += 2){
      loadChunk(c+1, pB, qB);
      doSteps(c, pA, qA);
      if (c + 2 < NC) loadChunk(c+2, pA, qA);
      doSteps(c+1, pB, qB);
    }
    return;
  }

  // ================== MFMA MLP path ==================
  __shared__ __bf16 w1f[16*32*8];   // [ct][l<32][j] B-frags layer1 (k>=16 lanes use zero reg)
  __shared__ __bf16 w2f[32*64*8];   // [kb*4+ct][l][j] B-frags layer2
  __shared__ float  b1s[256];
  __shared__ float  b2s[64];
  __shared__ float  w3s[512];
  __shared__ float  b3s[8];
  __shared__ __bf16 hbuf[8][16*72]; // per-wave h1-chunk / h2 transpose buffer

  int tid = threadIdx.x;

  // ---- stage weights ----
  for (int s = tid; s < 16*32*8; s += 512) w1f[s] = (__bf16)0.0f;
  __syncthreads();
  for (int idx = tid; idx < 15*256; idx += 512){   // w1: (k,n) k<15
    int k = idx >> 8, n = idx & 255;
    int ct = n >> 4;
    int l  = ((k>>3)*16) + (n & 15);               // l in [0,32)
    int j  = k & 7;
    w1f[(ct*32 + l)*8 + j] = (__bf16)w1[idx];
  }
  for (int idx = tid; idx < 256*64; idx += 512){   // w2: (k,n)
    int k = idx >> 6, n = idx & 63;
    int kb = k >> 5;
    int lq = (k >> 3) & 3;
    int j  = k & 7;
    int ct = n >> 4;
    int l  = lq*16 + (n & 15);
    w2f[((kb*4 + ct)*64 + l)*8 + j] = (__bf16)w2[idx];
  }
  if (tid < 256) b1s[tid] = b1[tid];
  if (tid < 64)  b2s[tid] = b2[tid];
  if (tid < 512) w3s[tid] = w3[tid];
  if (tid < 8)   b3s[tid] = b3[tid];
  __syncthreads();

  int lane = tid & 63;
  int wv   = tid >> 6;
  int m    = lane & 15;      // A-row (and C-col) position
  int q    = lane >> 4;
  int r0   = (blockIdx.x - 1)*128 + wv*16;

  // ---- build layer1 A-frag from attrs (k<15 real, rest zero) ----
  int rowA = r0 + m;
  int bA = rowA & (B_-1), tA = rowA >> 8;
  const float* ap = in + ((size_t)bA*T_ + tA)*F_ + 5;
  bf16x8 a1;
  #pragma unroll
  for (int j = 0; j < 8; ++j){
    int k = q*8 + j;
    float v = (k < 15) ? ap[k] : 0.0f;
    a1[j] = (__bf16)v;
  }

  __bf16* hb = &hbuf[wv][0];
  f32x4 zero4 = {0.0f, 0.0f, 0.0f, 0.0f};
  bf16x8 zero8;
  #pragma unroll
  for (int j = 0; j < 8; ++j) zero8[j] = (__bf16)0.0f;

  f32x4 acc2[4] = {zero4, zero4, zero4, zero4};

  // ---- phased L1 (MFMA) -> LDS transpose -> L2 (MFMA) ----
  #pragma unroll
  for (int p = 0; p < 4; ++p){
    #pragma unroll
    for (int c4 = 0; c4 < 4; ++c4){
      int ct = p*4 + c4;
      bf16x8 bw = zero8;
      if (lane < 32) bw = *(const bf16x8*)&w1f[(ct*32 + lane)*8];
      f32x4 c1 = __builtin_amdgcn_mfma_f32_16x16x32_bf16(a1, bw, zero4, 0, 0, 0);
      int f = c4*16 + m;                  // feature within this 64-chunk
      float bb = b1s[p*64 + f];
      #pragma unroll
      for (int i = 0; i < 4; ++i){
        float h = tanh_f(c1[i] + bb);
        hb[(q*4 + i)*72 + f] = (__bf16)h; // [row][feat]
      }
    }
    // consume chunk: K-blocks 2p, 2p+1  (same-wave LDS ops are in-order; no barrier needed)
    #pragma unroll
    for (int kb = 0; kb < 2; ++kb){
      bf16x8 a2 = *(const bf16x8*)&hb[m*72 + q*8 + kb*32];
      #pragma unroll
      for (int ct = 0; ct < 4; ++ct){
        bf16x8 bw2 = *(const bf16x8*)&w2f[(((p*2 + kb)*4 + ct)*64 + lane)*8];
        acc2[ct] = __builtin_amdgcn_mfma_f32_16x16x32_bf16(a2, bw2, acc2[ct], 0, 0, 0);
      }
    }
  }

  // ---- h2 = tanh(acc2 + b2) -> LDS [row][feat] (overwrites hb) ----
  #pragma unroll
  for (int ct = 0; ct < 4; ++ct){
    int f = ct*16 + m;
    float bb = b2s[f];
    #pragma unroll
    for (int i = 0; i < 4; ++i){
      float h = tanh_f(acc2[ct][i] + bb);
      hb[(q*4 + i)*72 + f] = (__bf16)h;
    }
  }

  // ---- L3 fp32 vector: lane -> (row m, outputs 2q, 2q+1) ----
  float z0 = b3s[2*q], z1 = b3s[2*q + 1];
  #pragma unroll
  for (int kb3 = 0; kb3 < 8; ++kb3){
    bf16x8 hv8 = *(const bf16x8*)&hb[m*72 + kb3*8];
    #pragma unroll
    for (int j = 0; j < 8; ++j){
      float hv = (float)hv8[j];
      int k = kb3*8 + j;
      z0 = fmaf(hv, w3s[k*8 + 2*q],     z0);
      z1 = fmaf(hv, w3s[k*8 + 2*q + 1], z1);
    }
  }
  int rowO = r0 + m;
  float2 outp = make_float2(sigmoid_f(z0), sigmoid_f(z1));
  *(float2*)&params[(size_t)rowO*8 + 2*q] = outp;
}

__global__ __launch_bounds__(256) void final_kernel(const float* __restrict__ ws,
                                                    float* __restrict__ out){
  int r = blockIdx.x*256 + threadIdx.x;
  if (r >= NT) return;
  const float* pT   = ws + NT;
  const float* wuT  = ws + 2*(size_t)NT;
  const float* wdT  = ws + 4*(size_t)NT;
  const float* params = ws + 5*(size_t)NT;

  float p  = pT[r];
  float wu = wuT[r], wd = wdT[r];
  const float4* pp = (const float4*)(params + (size_t)r*8);
  float4 p0 = pp[0], p1 = pp[1];
  // p0: wum, wlm, wdm, b  |  p1: c, k1, k2, k3
  // reference calls _runoff(wu, wd, wl, p, wum, wdm, wlm, b, c):
  //   state wd lands in the "wl" slot; param wdm in "wlm" slot; param wlm in "wdm" slot
  float wum   = fmaf(p0.x, 19.9f, 0.1f);
  float wlm_s = fmaf(p0.z, 30.0f, 60.0f);
  float wdm_s = fmaf(p0.y, 60.0f, 60.0f);
  float cc = fmaf(p1.x, 0.19f, 0.01f);
  float bb = fmaf(p0.w, 0.30f, 0.10f);
  float wt = wum + wlm_s + wdm_s;
  float xu = wu / wt;
  float xd = wd / wt;
  float s  = cc*xu*xu + bb*xd*xd;
  float ps = p - s;
  float runoff = hside(ps)*ps;
  float k1p = fmaf(p1.y, 0.69f, 0.01f);
  float k2p = fmaf(p1.z, 0.69f, 0.01f);
  float k3p = fmaf(p1.w, 0.89f, 0.01f);
  float sr  = k1p*runoff;
  float itf = k2p*(runoff - sr);
  float bf  = k3p*(runoff - sr - itf);
  int b = r & (B_-1);
  int t = r >> 8;
  out[(size_t)b*T_ + t] = sr + 0.5f*itf + 0.25f*bf;
}

extern "C" void kernel_launch(void* const* d_in, const int* in_sizes, int n_in,
                              void* d_out, int out_size, void* d_ws, size_t ws_size,
                              hipStream_t stream) {
  const float* in = (const float*)d_in[0];
  const float* w1 = (const float*)d_in[1];
  const float* b1 = (const float*)d_in[2];
  const float* w2 = (const float*)d_in[3];
  const float* b2 = (const float*)d_in[4];
  const float* w3 = (const float*)d_in[5];
  const float* b3 = (const float*)d_in[6];
  float* out = (float*)d_out;
  float* ws  = (float*)d_ws;

  prep_kernel <<<NT/256,        256, 0, stream>>>(in, ws);
  fused_kernel<<<NT/128 + 1,    512, 0, stream>>>(in, w1, b1, w2, b2, w3, b3, ws);
  final_kernel<<<NT/256,        256, 0, stream>>>(ws, out);
}

// Round 3
// 220.852 us; speedup vs baseline: 2.0825x; 1.6239x over previous
//
#include <hip/hip_runtime.h>

#define B_ 256
#define T_ 2048
#define F_ 20
#define NT (B_*T_)
#define CH 16
#define NCH (T_/CH)   // 128 chunks

typedef __bf16 bf16x8 __attribute__((ext_vector_type(8)));
typedef float  f32x4  __attribute__((ext_vector_type(4)));

__device__ __forceinline__ float ex2(float x){ return __builtin_amdgcn_exp2f(x); }
__device__ __forceinline__ float rcpf_(float x){ return __builtin_amdgcn_rcpf(x); }

// 20*log2(e), 2*log2(e), log2(e)
#define K10F 28.853900817779268f
#define K1F   2.8853900817779268f
#define LOG2E 1.4426950408889634f

__device__ __forceinline__ float hside(float x){ return 1.0f - rcpf_(ex2(K10F*x) + 1.0f); }
__device__ __forceinline__ float tanh_f(float z){ return 1.0f - 2.0f*rcpf_(ex2(K1F*z) + 1.0f); }
__device__ __forceinline__ float sigmoid_f(float z){ return rcpf_(1.0f + ex2(-LOG2E*z)); }

// ws float layout:
// pp2   [0, 2NT)     float2 {pet, p}, t-major r = t*256 + b
// wuT   [2NT, 3NT)
// wdT   [3NT, 4NT)
// params[4NT, 12NT)  8 per row r

__global__ __launch_bounds__(256) void prep_kernel(const float* __restrict__ in,
                                                   float* __restrict__ ws){
  int r = blockIdx.x*256 + threadIdx.x;
  if (r >= NT) return;
  int b = r & (B_-1);
  int t = r >> 8;
  const float* src = in + ((size_t)b*T_ + t)*F_;
  ((float2*)ws)[r] = make_float2(src[0], src[2]);  // pet, p
}

// blocks 0..3: pipelined scan (64 batches each, 4 pipeline waves)
// blocks 4..4099: MFMA MLP (128 rows each)
__global__ __launch_bounds__(512) void fused_kernel(const float* __restrict__ in,
    const float* __restrict__ w1, const float* __restrict__ b1,
    const float* __restrict__ w2, const float* __restrict__ b2,
    const float* __restrict__ w3, const float* __restrict__ b3,
    float* __restrict__ ws){
  extern __shared__ char sm[];
  float* params = ws + 4*(size_t)NT;

  if (blockIdx.x < 4) {
    // ================== pipelined Xinanjiang scan ==================
    const float2* pp2 = (const float2*)ws;
    float* wuT = ws + 2*(size_t)NT;
    float* wdT = ws + 3*(size_t)NT;
    float*  d1L = (float*)sm;                  // [2][CH][64]   8 KB
    float*  bsQ = (float*)(sm + 8192);         // [4][CH][64]  16 KB
    float2* rhL = (float2*)(sm + 24576);       // [2][CH][64]  16 KB {rp,hrp}
    float2* qbL = (float2*)(sm + 40960);       // [2][CH][64]  16 KB {qv,b2}

    int tid = threadIdx.x;
    int wv = tid >> 6, lane = tid & 63;
    int boff = blockIdx.x * 64;

    float wu = 0.0f, wl = 0.0f, wd = 0.0f;
    float2 buf[2][8];

    if (wv == 0){
      #pragma unroll
      for (int g = 0; g < 2; ++g)
        #pragma unroll
        for (int i = 0; i < 8; ++i)
          buf[g][i] = pp2[(g*8 + i)*B_ + boff + lane];
    }

    for (int it = 0; it < NCH + 3; ++it){
      if (wv == 0){
        if (it < NCH){
          int c = it, par = c & 1;
          #pragma unroll
          for (int g = 0; g < 2; ++g){
            #pragma unroll
            for (int i = 0; i < 8; ++i){
              int s = g*8 + i;
              float pet = buf[g][i].x, p = buf[g][i].y;
              float d  = wu - pet;
              float r1 = rcpf_(ex2(K10F*d) + 1.0f);
              float d1 = -d*r1;                       // pet - et1
              float base = (p - pet) + d1;            // p - et1
              wu += base;
              wuT[(c*CH + s)*B_ + boff + lane] = wu;
              d1L[par*(CH*64) + s*64 + lane] = d1;
              bsQ[(c&3)*(CH*64) + s*64 + lane] = base;
            }
            int cn = (c + 1 < NCH) ? c + 1 : c;       // prefetch next chunk, same group
            #pragma unroll
            for (int i = 0; i < 8; ++i)
              buf[g][i] = pp2[(cn*CH + g*8 + i)*B_ + boff + lane];
          }
        }
      } else if (wv == 1){
        if (it >= 1 && it <= NCH){
          int c = it - 1, par = c & 1;
          #pragma unroll
          for (int s = 0; s < CH; ++s){
            float d1 = d1L[par*(CH*64) + s*64 + lane];
            float r2 = rcpf_(ex2(K10F*d1) + 1.0f);
            float rp = fmaf(-d1, r2, d1);             // h(d1)*d1
            float hrp = 1.0f - rcpf_(ex2(K10F*rp) + 1.0f);
            rhL[par*(CH*64) + s*64 + lane] = make_float2(rp, hrp);
          }
        }
      } else if (wv == 2){
        if (it >= 2 && it <= NCH + 1){
          int c = it - 2, par = c & 1;
          #pragma unroll
          for (int s = 0; s < CH; ++s){
            float2 rh  = rhL[par*(CH*64) + s*64 + lane];
            float base = bsQ[(c&3)*(CH*64) + s*64 + lane];
            float d2   = rh.x - wl;
            float r    = rcpf_(ex2(K10F*d2) + 1.0f);
            float et22 = fmaf(d2, r, wl);
            float et2  = rh.y * et22;
            float b2   = base - et2;                  // base - et2
            wl += b2;
            qbL[par*(CH*64) + s*64 + lane] = make_float2(rh.x - et2, b2); // qv, b2
          }
        }
      } else if (wv == 3){
        if (it >= 3){
          int c = it - 3, par = c & 1;
          #pragma unroll
          for (int s = 0; s < CH; ++s){
            float2 qb  = qbL[par*(CH*64) + s*64 + lane];
            float hqv  = 1.0f - rcpf_(ex2(K10F*qb.x) + 1.0f);
            float d3   = qb.x - wd;
            float r    = rcpf_(ex2(K10F*d3) + 1.0f);
            float et33 = fmaf(d3, r, wd);
            float et3  = hqv * et33;
            wd += qb.y - et3;
            wdT[(c*CH + s)*B_ + boff + lane] = wd;
          }
        }
      }
      __syncthreads();
    }
    return;
  }

  // ================== MFMA MLP path ==================
  __bf16* w1f  = (__bf16*)sm;                // [ct][l<32][j]  8192 B
  __bf16* w2f  = (__bf16*)(sm + 8192);       // [kb*4+ct][l][j] 32768 B
  float*  b1s  = (float*)(sm + 40960);
  float*  b2s  = (float*)(sm + 41984);
  float*  w3s  = (float*)(sm + 42240);
  float*  b3s  = (float*)(sm + 44288);
  __bf16* hbufA= (__bf16*)(sm + 44320);      // 8 waves × 16×72 bf16

  int tid = threadIdx.x;

  for (int s = tid; s < 16*32*8; s += 512) w1f[s] = (__bf16)0.0f;
  __syncthreads();
  for (int idx = tid; idx < 15*256; idx += 512){   // w1: (k,n) k<15
    int k = idx >> 8, n = idx & 255;
    int ct = n >> 4;
    int l  = ((k>>3)*16) + (n & 15);
    int j  = k & 7;
    w1f[(ct*32 + l)*8 + j] = (__bf16)w1[idx];
  }
  for (int idx = tid; idx < 256*64; idx += 512){   // w2: (k,n)
    int k = idx >> 6, n = idx & 63;
    int kb = k >> 5;
    int lq = (k >> 3) & 3;
    int j  = k & 7;
    int ct = n >> 4;
    int l  = lq*16 + (n & 15);
    w2f[((kb*4 + ct)*64 + l)*8 + j] = (__bf16)w2[idx];
  }
  if (tid < 256) b1s[tid] = b1[tid];
  if (tid < 64)  b2s[tid] = b2[tid];
  if (tid < 512) w3s[tid] = w3[tid];
  if (tid < 8)   b3s[tid] = b3[tid];
  __syncthreads();

  int lane = tid & 63;
  int wv   = tid >> 6;
  int m    = lane & 15;
  int q    = lane >> 4;
  int r0   = (blockIdx.x - 4)*128 + wv*16;

  int rowA = r0 + m;
  int bA = rowA & (B_-1), tA = rowA >> 8;
  const float* ap = in + ((size_t)bA*T_ + tA)*F_ + 5;
  bf16x8 a1;
  #pragma unroll
  for (int j = 0; j < 8; ++j){
    int k = q*8 + j;
    float v = (k < 15) ? ap[k] : 0.0f;
    a1[j] = (__bf16)v;
  }

  __bf16* hb = hbufA + wv*1152;
  f32x4 zero4 = {0.0f, 0.0f, 0.0f, 0.0f};
  bf16x8 zero8;
  #pragma unroll
  for (int j = 0; j < 8; ++j) zero8[j] = (__bf16)0.0f;

  f32x4 acc2[4] = {zero4, zero4, zero4, zero4};

  #pragma unroll
  for (int p = 0; p < 4; ++p){
    #pragma unroll
    for (int c4 = 0; c4 < 4; ++c4){
      int ct = p*4 + c4;
      bf16x8 bw = zero8;
      if (lane < 32) bw = *(const bf16x8*)&w1f[(ct*32 + lane)*8];
      f32x4 c1 = __builtin_amdgcn_mfma_f32_16x16x32_bf16(a1, bw, zero4, 0, 0, 0);
      int f = c4*16 + m;
      float bb = b1s[p*64 + f];
      #pragma unroll
      for (int i = 0; i < 4; ++i){
        float h = tanh_f(c1[i] + bb);
        hb[(q*4 + i)*72 + f] = (__bf16)h;
      }
    }
    #pragma unroll
    for (int kb = 0; kb < 2; ++kb){
      bf16x8 a2 = *(const bf16x8*)&hb[m*72 + q*8 + kb*32];
      #pragma unroll
      for (int ct = 0; ct < 4; ++ct){
        bf16x8 bw2 = *(const bf16x8*)&w2f[(((p*2 + kb)*4 + ct)*64 + lane)*8];
        acc2[ct] = __builtin_amdgcn_mfma_f32_16x16x32_bf16(a2, bw2, acc2[ct], 0, 0, 0);
      }
    }
  }

  #pragma unroll
  for (int ct = 0; ct < 4; ++ct){
    int f = ct*16 + m;
    float bb = b2s[f];
    #pragma unroll
    for (int i = 0; i < 4; ++i){
      float h = tanh_f(acc2[ct][i] + bb);
      hb[(q*4 + i)*72 + f] = (__bf16)h;
    }
  }

  float z0 = b3s[2*q], z1 = b3s[2*q + 1];
  #pragma unroll
  for (int kb3 = 0; kb3 < 8; ++kb3){
    bf16x8 hv8 = *(const bf16x8*)&hb[m*72 + kb3*8];
    #pragma unroll
    for (int j = 0; j < 8; ++j){
      float hv = (float)hv8[j];
      int k = kb3*8 + j;
      z0 = fmaf(hv, w3s[k*8 + 2*q],     z0);
      z1 = fmaf(hv, w3s[k*8 + 2*q + 1], z1);
    }
  }
  int rowO = r0 + m;
  float2 outp = make_float2(sigmoid_f(z0), sigmoid_f(z1));
  *(float2*)&params[(size_t)rowO*8 + 2*q] = outp;
}

__global__ __launch_bounds__(256) void final_kernel(const float* __restrict__ ws,
                                                    float* __restrict__ out){
  int r = blockIdx.x*256 + threadIdx.x;
  if (r >= NT) return;
  const float2* pp2 = (const float2*)ws;
  const float* wuT  = ws + 2*(size_t)NT;
  const float* wdT  = ws + 3*(size_t)NT;
  const float* params = ws + 4*(size_t)NT;

  float p  = pp2[r].y;
  float wu = wuT[r], wd = wdT[r];
  const float4* pp = (const float4*)(params + (size_t)r*8);
  float4 p0 = pp[0], p1 = pp[1];
  // reference calls _runoff(wu, wd, wl, p, wum, wdm, wlm, b, c):
  //   state wd lands in the "wl" slot; param wdm in "wlm" slot; param wlm in "wdm" slot
  float wum   = fmaf(p0.x, 19.9f, 0.1f);
  float wlm_s = fmaf(p0.z, 30.0f, 60.0f);
  float wdm_s = fmaf(p0.y, 60.0f, 60.0f);
  float cc = fmaf(p1.x, 0.19f, 0.01f);
  float bb = fmaf(p0.w, 0.30f, 0.10f);
  float wt = wum + wlm_s + wdm_s;
  float xu = wu / wt;
  float xd = wd / wt;
  float s  = cc*xu*xu + bb*xd*xd;
  float ps = p - s;
  float runoff = hside(ps)*ps;
  float k1p = fmaf(p1.y, 0.69f, 0.01f);
  float k2p = fmaf(p1.z, 0.69f, 0.01f);
  float k3p = fmaf(p1.w, 0.89f, 0.01f);
  float sr  = k1p*runoff;
  float itf = k2p*(runoff - sr);
  float bf  = k3p*(runoff - sr - itf);
  int b = r & (B_-1);
  int t = r >> 8;
  out[(size_t)b*T_ + t] = sr + 0.5f*itf + 0.25f*bf;
}

extern "C" void kernel_launch(void* const* d_in, const int* in_sizes, int n_in,
                              void* d_out, int out_size, void* d_ws, size_t ws_size,
                              hipStream_t stream) {
  const float* in = (const float*)d_in[0];
  const float* w1 = (const float*)d_in[1];
  const float* b1 = (const float*)d_in[2];
  const float* w2 = (const float*)d_in[3];
  const float* b2 = (const float*)d_in[4];
  const float* w3 = (const float*)d_in[5];
  const float* b3 = (const float*)d_in[6];
  float* out = (float*)d_out;
  float* ws  = (float*)d_ws;

  prep_kernel <<<NT/256,      256, 0,     stream>>>(in, ws);
  fused_kernel<<<NT/128 + 4,  512, 62752, stream>>>(in, w1, b1, w2, b2, w3, b3, ws);
  final_kernel<<<NT/256,      256, 0,     stream>>>(ws, out);
}